// Round 4
// baseline (255.050 us; speedup 1.0000x reference)
//
#include <hip/hip_runtime.h>
#include <stdint.h>

// Problem constants
#define BB 4
#define SS 2048
#define PP 8
#define FIN 1024
#define FOUT 1024
#define MROWS (BB*SS)          // 8192 rows per group
#define ROWSTRIDE (PP*FIN)     // 8192 floats between consecutive (b,s) rows
#define OROWSTRIDE (PP*FOUT)

// Tile config: 256x256, BK=64, 512 threads (8 waves as 2m x 4n)
#define BM 256
#define BN 256
#define BK 64
#define NKT (FIN/BK)           // 16 K-tiles

typedef float fx4 __attribute__((ext_vector_type(4)));
typedef short sv8 __attribute__((ext_vector_type(8)));   // 8 bf16 (MFMA frag)

union BCvt { sv8 s; __bf16 b[8]; };

__device__ __forceinline__ unsigned short bfbits(float f) {
    union { __bf16 b; unsigned short u; } c; c.b = (__bf16)f; return c.u;
}
__device__ __forceinline__ sv8 cvt8(fx4 lo, fx4 hi) {
    BCvt u;
#pragma unroll
    for (int i = 0; i < 4; ++i) { u.b[i] = (__bf16)lo[i]; u.b[i + 4] = (__bf16)hi[i]; }
    return u.s;
}

// ---------------------------------------------------------------------------
// Prepass: W [P][K][N] fp32 -> Wt tiled+swizzled bf16 (16.8 MB in d_ws).
// Tile (p, nt, kt) = contiguous 32 KB = two 16 KB half-images (n-halves):
//   byte_in_tile = n*128 + ((kg*16) ^ ((n&7)<<4)), kg = k/8, n in [0,256)
// (n in [0,128) = half 0 occupies the first 16 KB -> halves are contiguous)
// ---------------------------------------------------------------------------
__global__ __launch_bounds__(256) void wtrans(const float* __restrict__ w,
                                              unsigned short* __restrict__ wt) {
    __shared__ unsigned short L[64][260];
    const int bid = blockIdx.x;              // 8*4*16 = 512 blocks
    const int p  = bid >> 6;
    const int nt = (bid >> 4) & 3;
    const int kt = bid & 15;
    const int k0 = kt * 64, n0 = nt * 256;
    const int t = threadIdx.x;

    const int nf = t & 63, kseg = t >> 6;
#pragma unroll
    for (int rr = 0; rr < 16; ++rr) {
        const int k = kseg * 16 + rr;
        fx4 v = *(const fx4*)(w + (size_t)p * (FIN*FOUT) + (size_t)(k0 + k) * FOUT + n0 + nf * 4);
        L[k][nf*4+0] = bfbits(v[0]); L[k][nf*4+1] = bfbits(v[1]);
        L[k][nf*4+2] = bfbits(v[2]); L[k][nf*4+3] = bfbits(v[3]);
    }
    __syncthreads();

    unsigned short* tile = wt + (size_t)((p * 4 + nt) * 16 + kt) * 16384;
    const int n = t;  // 0..255
#pragma unroll
    for (int kg = 0; kg < 8; ++kg) {
        union { sv8 s; unsigned short us[8]; } u;
#pragma unroll
        for (int e = 0; e < 8; ++e) u.us[e] = L[kg * 8 + e][n];
        const int byte_ = n * 128 + ((kg * 16) ^ ((n & 7) << 4));
        *(sv8*)((char*)tile + byte_) = u.s;
    }
}

// ---------------------------------------------------------------------------
// 256x256 grouped GEMM, 8-phase counted-vmcnt schedule (m201 port).
// Per K-tile: 4 phases {ds_read quadrant frags; stage ONE half-tile;
// barrier; setprio 16xMFMA setprio; barrier}. vmcnt(8) once per tile.
// ---------------------------------------------------------------------------
#define STR2(x) #x
#define VMBAR(N) do {                                                          \
    asm volatile("s_waitcnt vmcnt(" STR2(N) ") lgkmcnt(0)" ::: "memory");      \
    __builtin_amdgcn_s_barrier();                                              \
} while (0)
#define LGKBAR do {                                                            \
    asm volatile("s_waitcnt lgkmcnt(0)" ::: "memory");                         \
    __builtin_amdgcn_s_barrier();                                              \
} while (0)
#define BAR __builtin_amdgcn_s_barrier()

// A half: thread (arow = tid>>2 in [0,128), akq = tid&3): 16 contiguous fp32
#define LOADA_HALF(kt, h, r) do {                                              \
    const float* s_ = x + (size_t)(m0 + (h) * 128 + arow) * ROWSTRIDE          \
                        + p * FIN + (kt) * BK + akq * 16;                      \
    r[0] = *(const fx4*)s_;       r[1] = *(const fx4*)(s_ + 4);                \
    r[2] = *(const fx4*)(s_ + 8); r[3] = *(const fx4*)(s_ + 12);               \
} while (0)

// cvt + 2 x ds_write_b128 into swizzled half image (16 KB)
#define STOREA_HALF(dst, r) do {                                               \
    const int sw_ = (arow & 7) << 4;                                           \
    char* bp_ = (dst) + arow * 128;                                            \
    *(sv8*)(bp_ + (((akq * 2) * 16)     ^ sw_)) = cvt8(r[0], r[1]);            \
    *(sv8*)(bp_ + (((akq * 2 + 1) * 16) ^ sw_)) = cvt8(r[2], r[3]);            \
} while (0)

// B half: 16 KB via 2 x global_load_lds width-16 (pre-swizzled source)
#define GLOADB_HALF(kt, dst, h) do {                                           \
    const char* gb_ = (const char*)btile + (size_t)(kt) * 32768 + (h) * 16384; \
    _Pragma("unroll")                                                          \
    for (int c_ = 0; c_ < 2; ++c_) {                                           \
        __builtin_amdgcn_global_load_lds(                                      \
            (const __attribute__((address_space(1))) void*)(gb_ + c_ * 8192 + tid * 16), \
            (__attribute__((address_space(3))) void*)((dst) + c_ * 8192 + tid * 16),     \
            16, 0, 0);                                                         \
    }                                                                          \
} while (0)

// wave wm owns A-half wm; mh selects 64-row sub-block: 8 x ds_read_b128
#define READ_A(srcb, mh) do {                                                  \
    _Pragma("unroll")                                                          \
    for (int i = 0; i < 4; ++i) {                                              \
        const int row_ = (mh) * 64 + i * 16 + (lane & 15);                     \
        const char* bp_ = (srcb) + row_ * 128;                                 \
        const int sw_ = (row_ & 7) << 4;                                       \
        _Pragma("unroll")                                                      \
        for (int ks = 0; ks < 2; ++ks)                                         \
            af[i][ks] = *(const sv8*)(bp_ + ((ks * 64 + (lane >> 4) * 16) ^ sw_)); \
    }                                                                          \
} while (0)

// wave wn reads from B-half (wn>>1), rows (wn&1)*64 + nh*32 + ...: 4 reads
#define READ_B(srcb, nh, dst) do {                                             \
    _Pragma("unroll")                                                          \
    for (int j = 0; j < 2; ++j) {                                              \
        const int row_ = (wn & 1) * 64 + (nh) * 32 + j * 16 + (lane & 15);     \
        const char* bp_ = (srcb) + row_ * 128;                                 \
        const int sw_ = (row_ & 7) << 4;                                       \
        _Pragma("unroll")                                                      \
        for (int ks = 0; ks < 2; ++ks)                                         \
            dst[j][ks] = *(const sv8*)(bp_ + ((ks * 64 + (lane >> 4) * 16) ^ sw_)); \
    }                                                                          \
} while (0)

#define MFMA_Q(mh, nh, bfr) do {                                               \
    __builtin_amdgcn_s_setprio(1);                                             \
    _Pragma("unroll")                                                          \
    for (int i = 0; i < 4; ++i)                                                \
        _Pragma("unroll")                                                      \
        for (int j = 0; j < 2; ++j)                                            \
            _Pragma("unroll")                                                  \
            for (int ks = 0; ks < 2; ++ks)                                     \
                acc[(mh)*4+i][(nh)*2+j] = __builtin_amdgcn_mfma_f32_16x16x32_bf16( \
                    af[i][ks], bfr[j][ks], acc[(mh)*4+i][(nh)*2+j], 0, 0, 0);  \
    __builtin_amdgcn_s_setprio(0);                                             \
} while (0)

// One K-tile = 4 phases. cur = parity par, stage into par^1.
// Ledger (entry invariant: 8 A(t+1) loads outstanding, cur bufs staged):
//  p0: +2 gloadB(t+1)h0   -> 10
//  p1: +2 gloadB(t+1)h1   -> 12
//  p2: STOREA h0 (compiler vmcnt(8): rA0 oldest, no stall); +4 A(t+2)h0 -> 12
//  p3: STOREA h1; +4 A(t+2)h1 -> 16-4(retired)=...; VMBAR(8) retires B(t+1),
//      leaves the 8 A(t+2) loads in flight. Invariant restored.
#define TILE_BODY(t, par) do {                                                 \
    char* Ac0 = ldsA[par][0];   char* Ac1 = ldsA[par][1];                      \
    char* Bc  = ldsB[par][wn >> 1];                                            \
    char* An0 = ldsA[par ^ 1][0]; char* An1 = ldsA[par ^ 1][1];                \
    char* Bn0 = ldsB[par ^ 1][0]; char* Bn1 = ldsB[par ^ 1][1];                \
    char* Ac  = wm ? Ac1 : Ac0;                                                \
    const bool stage = (t) < 15, pref = (t) < 14;                              \
    /* phase 0: quadrant (0,0) */                                              \
    READ_A(Ac, 0); READ_B(Bc, 0, bf0);                                         \
    if (stage) GLOADB_HALF((t) + 1, Bn0, 0);                                   \
    BAR; MFMA_Q(0, 0, bf0); BAR;                                               \
    /* phase 1: quadrant (0,1) */                                              \
    READ_B(Bc, 1, bf1);                                                        \
    if (stage) GLOADB_HALF((t) + 1, Bn1, 1);                                   \
    BAR; MFMA_Q(0, 1, bf1); BAR;                                               \
    /* phase 2: quadrant (1,1) */                                              \
    READ_A(Ac, 1);                                                             \
    if (stage) STOREA_HALF(An0, rA0);                                          \
    if (pref)  LOADA_HALF((t) + 2, 0, rA0);                                    \
    BAR; MFMA_Q(1, 1, bf1); BAR;                                               \
    /* phase 3: quadrant (1,0) */                                              \
    if (stage) STOREA_HALF(An1, rA1);                                          \
    if (pref)  LOADA_HALF((t) + 2, 1, rA1);                                    \
    if (pref)       VMBAR(8);                                                  \
    else if (stage) VMBAR(0);   /* t==14: only B(15) outstanding */            \
    else            LGKBAR;     /* t==15 */                                    \
    MFMA_Q(1, 0, bf0); BAR;                                                    \
} while (0)

__global__ __launch_bounds__(512, 1)
void pd_gemm(const float* __restrict__ x, const unsigned short* __restrict__ wt,
             const float* __restrict__ bias, float* __restrict__ out) {
    __shared__ __align__(16) char ldsA[2][2][16384];   // [dbuf][half] 64 KB
    __shared__ __align__(16) char ldsB[2][2][16384];   // 64 KB

    const int tid = threadIdx.x;
    const int lane = tid & 63;
    const int wv = tid >> 6;            // 8 waves: 2(m) x 4(n)
    const int wm = wv >> 2, wn = wv & 3;

    // 1024 blocks; p == XCD (bijective, 1024%8==0); n fastest within p
    const int bid = blockIdx.x;
    const int p   = bid & 7;
    const int wrk = bid >> 3;           // 0..127
    const int n0  = (wrk & 3) * BN;
    const int m0  = (wrk >> 2) * BM;

    const int arow = tid >> 2, akq = tid & 3;   // A staging map
    const unsigned short* btile = wt + (size_t)((p * 4 + (n0 >> 8)) * 16) * 16384;

    fx4 acc[8][4];
#pragma unroll
    for (int i = 0; i < 8; ++i)
#pragma unroll
        for (int j = 0; j < 4; ++j) acc[i][j] = (fx4)0.0f;

    fx4 rA0[4], rA1[4];
    sv8 af[4][2], bf0[2][2], bf1[2][2];

    // Prologue: stage tile 0 into dbuf 0; issue A(1); establish invariant.
    LOADA_HALF(0, 0, rA0); LOADA_HALF(0, 1, rA1);   // 8 loads
    GLOADB_HALF(0, ldsB[0][0], 0); GLOADB_HALF(0, ldsB[0][1], 1);  // 4
    STOREA_HALF(ldsA[0][0], rA0);   // compiler waits rA0 (oldest), B stays
    STOREA_HALF(ldsA[0][1], rA1);
    LOADA_HALF(1, 0, rA0); LOADA_HALF(1, 1, rA1);   // 8 loads for tile 1
    VMBAR(8);   // retire gloadB(0) (4 oldest); A(1)'s 8 remain in flight

#pragma unroll 1
    for (int kk = 0; kk < 8; ++kk) {
        const int t = 2 * kk;
        TILE_BODY(t, 0);
        TILE_BODY(t + 1, 1);
    }

    // Epilogue: C/D map col = lane&15, row = (lane>>4)*4 + j
    const float* bs = bias + p * FOUT;
#pragma unroll
    for (int nf = 0; nf < 4; ++nf) {
        const int col = n0 + wn * 64 + nf * 16 + (lane & 15);
        const float bv = bs[col];
#pragma unroll
        for (int mf = 0; mf < 8; ++mf) {
            const int row = m0 + wm * 128 + mf * 16 + (lane >> 4) * 4;
            float* o = out + (size_t)row * OROWSTRIDE + p * FOUT + col;
#pragma unroll
            for (int j = 0; j < 4; ++j)
                o[j * OROWSTRIDE] = acc[mf][nf][j] + bv;
        }
    }
}

// Fallback if d_ws can't hold Wt (never observed): correct but slow.
__global__ __launch_bounds__(256) void pd_naive(const float* __restrict__ x,
                                                const float* __restrict__ w,
                                                const float* __restrict__ bias,
                                                float* __restrict__ out) {
    const long long total = (long long)MROWS * PP * FOUT;
    for (long long idx = blockIdx.x * 256LL + threadIdx.x; idx < total;
         idx += (long long)gridDim.x * 256) {
        const int n = (int)(idx & 1023);
        const int p = (int)((idx >> 10) & 7);
        const long long m = idx >> 13;
        const float* xr = x + m * ROWSTRIDE + p * FIN;
        const float* wc = w + (size_t)p * (FIN*FOUT) + n;
        float s = bias[p * FOUT + n];
        for (int k = 0; k < FIN; ++k) s += xr[k] * wc[(size_t)k * FOUT];
        out[idx] = s;
    }
}

extern "C" void kernel_launch(void* const* d_in, const int* in_sizes, int n_in,
                              void* d_out, int out_size, void* d_ws, size_t ws_size,
                              hipStream_t stream) {
    const float* x    = (const float*)d_in[0];
    const float* w    = (const float*)d_in[1];
    const float* bias = (const float*)d_in[2];
    float* out = (float*)d_out;

    const size_t WT_BYTES = (size_t)PP * FIN * FOUT * sizeof(unsigned short);  // 16.8 MB
    if (ws_size >= WT_BYTES) {
        unsigned short* wt = (unsigned short*)d_ws;
        wtrans<<<dim3(512), dim3(256), 0, stream>>>(w, wt);
        const int nblk = PP * (MROWS / BM) * (FOUT / BN);   // 8*32*4 = 1024
        pd_gemm<<<dim3(nblk), dim3(512), 0, stream>>>(x, wt, bias, out);
    } else {
        pd_naive<<<dim3(2048), dim3(256), 0, stream>>>(x, w, bias, out);
    }
}